// Round 7
// baseline (13804.907 us; speedup 1.0000x reference)
//
#include <hip/hip_runtime.h>
#include <hip/hip_fp16.h>

#define B_   128
#define L_   1024
#define DIN  64
#define H_   512
#define DOUT 64

typedef _Float16 half8 __attribute__((ext_vector_type(8)));
typedef float    f32x4 __attribute__((ext_vector_type(4)));

#define FSTR 16            // flag stride in ints (64B)
#define SPIN_CAP (1<<20)   // busy-poll cap: protocol bug -> wrong answer, not hang

#define MFMA16(a,b,c) __builtin_amdgcn_mfma_f32_16x16x32_f16((a),(b),(c),0,0,0)
#define PINH8(x) asm volatile("" : "+v"(x))
#define AGENT_ST(p, v) __hip_atomic_store((p), (v), __ATOMIC_RELAXED, __HIP_MEMORY_SCOPE_AGENT)
#define AGENT_LD(p)    __hip_atomic_load((p), __ATOMIC_RELAXED, __HIP_MEMORY_SCOPE_AGENT)

// ---------------- flag init (re-run every launch -> graph-replay safe) ----------------
__global__ void k_init_flags(int* flags) {
    int i = threadIdx.x;
    if (i < 256) flags[i * FSTR] = -1;
}

// ---------------- cast weights to f16 + bias sums ----------------
__global__ void k_prep_w(const float* __restrict__ whh0, const float* __restrict__ wih1,
                         const float* __restrict__ whh1, const float* __restrict__ wout,
                         const float* __restrict__ bih0, const float* __restrict__ bhh0,
                         const float* __restrict__ bih1, const float* __restrict__ bhh1,
                         _Float16* __restrict__ o0, _Float16* __restrict__ o1,
                         _Float16* __restrict__ o2, _Float16* __restrict__ o3,
                         float* __restrict__ b0s, float* __restrict__ b1s) {
    const int NW = H_ * H_;
    const int total = 3 * NW + DOUT * H_ + 2 * H_;
    int i  = blockIdx.x * blockDim.x + threadIdx.x;
    int st = gridDim.x * blockDim.x;
    for (; i < total; i += st) {
        if      (i < NW)            o0[i]          = (_Float16)whh0[i];
        else if (i < 2 * NW)        o1[i - NW]     = (_Float16)wih1[i - NW];
        else if (i < 3 * NW)        o2[i - 2 * NW] = (_Float16)whh1[i - 2 * NW];
        else if (i < 3 * NW + DOUT * H_) o3[i - 3 * NW] = (_Float16)wout[i - 3 * NW];
        else if (i < 3 * NW + DOUT * H_ + H_) {
            int j = i - (3 * NW + DOUT * H_);
            b0s[j] = bih0[j] + bhh0[j];
        } else {
            int j = i - (3 * NW + DOUT * H_ + H_);
            b1s[j] = bih1[j] + bhh1[j];
        }
    }
}

// ---------------- wcomb[g][d] = sum_h W_ih0[g][h] * W_in[h][d] (proj_in folded in) ----------------
__global__ void k_wcomb(const float* __restrict__ wih0, const float* __restrict__ win,
                        _Float16* __restrict__ o) {
    int g = blockIdx.x;    // 512
    int d = threadIdx.x;   // 64
    float acc = 0.f;
    for (int h = 0; h < H_; ++h)
        acc += wih0[g * H_ + h] * win[h * DIN + d];
    o[g * DIN + d] = (_Float16)acc;
}

// ---------------- helpers ----------------
__device__ __forceinline__ int spin_geq(const int* fp, int tgt, int cached) {
    if (cached >= tgt) return cached;   // cached-monotone: no traffic when satisfied
    int v = AGENT_LD(fp);
    int it = 0;
    while (v < tgt && ++it < SPIN_CAP) v = AGENT_LD(fp);
    return v;
}

__device__ __forceinline__ float tanh_fast(float v) {
    float e = __expf(2.f * v);
    return 1.f - 2.f / (e + 1.f);   // saturates correctly for large |v|
}

// 16 x 16B coherent loads from base + kt*64B, internal vmcnt(0): outputs VALID at asm end.
__device__ __forceinline__ void ld_frags16_sc(const _Float16* base, half8 f[16]) {
    asm volatile(
        "global_load_dwordx4 %0, %16, off sc0 sc1\n\t"
        "global_load_dwordx4 %1, %16, off offset:64 sc0 sc1\n\t"
        "global_load_dwordx4 %2, %16, off offset:128 sc0 sc1\n\t"
        "global_load_dwordx4 %3, %16, off offset:192 sc0 sc1\n\t"
        "global_load_dwordx4 %4, %16, off offset:256 sc0 sc1\n\t"
        "global_load_dwordx4 %5, %16, off offset:320 sc0 sc1\n\t"
        "global_load_dwordx4 %6, %16, off offset:384 sc0 sc1\n\t"
        "global_load_dwordx4 %7, %16, off offset:448 sc0 sc1\n\t"
        "global_load_dwordx4 %8, %16, off offset:512 sc0 sc1\n\t"
        "global_load_dwordx4 %9, %16, off offset:576 sc0 sc1\n\t"
        "global_load_dwordx4 %10, %16, off offset:640 sc0 sc1\n\t"
        "global_load_dwordx4 %11, %16, off offset:704 sc0 sc1\n\t"
        "global_load_dwordx4 %12, %16, off offset:768 sc0 sc1\n\t"
        "global_load_dwordx4 %13, %16, off offset:832 sc0 sc1\n\t"
        "global_load_dwordx4 %14, %16, off offset:896 sc0 sc1\n\t"
        "global_load_dwordx4 %15, %16, off offset:960 sc0 sc1\n\t"
        "s_waitcnt vmcnt(0)"
        : "=&v"(f[0]), "=&v"(f[1]), "=&v"(f[2]), "=&v"(f[3]),
          "=&v"(f[4]), "=&v"(f[5]), "=&v"(f[6]), "=&v"(f[7]),
          "=&v"(f[8]), "=&v"(f[9]), "=&v"(f[10]), "=&v"(f[11]),
          "=&v"(f[12]), "=&v"(f[13]), "=&v"(f[14]), "=&v"(f[15])
        : "v"(base)
        : "memory");
}

// ---------------- fused slack pipeline (sound data movement) ----------------
// grid = 96 blocks x 256 thr: g = bid&7, role = bid>>3 in [0,12):
//   role 0    : L0R  h0_t = tanh(wcomb*u_t + b0 + whh0*h0_{t-1})   [self-loop in LDS]
//   role 1    : L1R  h1_t = tanh(xw1_t + whh1*h1_{t-1})            [self-loop in LDS]
//   role 2,3  : G3_p y_t = wout*h1_t (parity p)
//   role 4..11: X1_{j,p} xw1_t slice j (parity p) = wih1*h0_t + b1
// Rings (depth 8): s1g (xw1), h0g, h1g — all accessed with agent-scope atomics or
// sc0sc1 asm with internal vmcnt(0). Producers drain (vmcnt(0)+barrier) before publish.
// Flags per group (base g*32): 0 FH0, 1 FC1, 2 FH1, 3+p FCH1, 8+2j+p FCH0, 16+2j+p FX1.
__global__ __launch_bounds__(256, 1)
void k_pipe3(const float* __restrict__ u,
             const _Float16* __restrict__ wcomb,   // [512][64]
             const _Float16* __restrict__ whh0w,   // [512][512]
             const _Float16* __restrict__ wih1w,   // [512][512]
             const _Float16* __restrict__ whh1w,   // [512][512]
             const _Float16* __restrict__ woutw,   // [64][512]
             const float* __restrict__ b0s, const float* __restrict__ b1s,
             float* __restrict__ out,              // [B_*L_][64] fp32
             _Float16* __restrict__ slot1,         // [8][8][8192]
             _Float16* __restrict__ h0s,           // [8][8][8192] ([16][512] each)
             _Float16* __restrict__ h1s,           // [8][8][8192]
             int* __restrict__ flags) {
    const int bid = blockIdx.x;
    const int g = bid & 7, role = bid >> 3;
    const int tid = threadIdx.x;
    const int l = tid & 63, w = tid >> 6;
    const int l15 = l & 15, lg = l >> 4, kofs = lg * 8;
    const int b0 = g * 16;
    int* F = flags + g * 32 * FSTR;
#define FLG(i) (F + (i) * FSTR)
    _Float16* s1g = slot1 + (size_t)g * 8 * 8192;
    _Float16* h0g = h0s + (size_t)g * 8 * 8192;
    _Float16* h1g = h1s + (size_t)g * 8 * 8192;

    __shared__ _Float16 hbuf[16][528];   // self-loop h(t-1) staging

    if (role <= 1) {
        // ================= L0R / L1R (recurrent cores) =================
        const bool L0 = (role == 0);
        const _Float16* whh = L0 ? whh0w : whh1w;
        _Float16* hdst = L0 ? h0g : h1g;
        const int c0 = w * 128;

        half8 wv[4][16];   // col-tiles 0..3 pinned in VGPRs; 4..7 streamed from L2
#pragma unroll
        for (int nt = 0; nt < 4; ++nt)
#pragma unroll
            for (int kt = 0; kt < 16; ++kt) {
                wv[nt][kt] = *(const half8*)(whh + (size_t)(c0 + nt * 16 + l15) * H_ + kt * 32 + kofs);
                PINH8(wv[nt][kt]);
            }
        const _Float16* wst4 = whh + (size_t)(c0 + 4 * 16 + l15) * H_ + kofs;
        const _Float16* wst5 = whh + (size_t)(c0 + 5 * 16 + l15) * H_ + kofs;
        const _Float16* wst6 = whh + (size_t)(c0 + 6 * 16 + l15) * H_ + kofs;
        const _Float16* wst7 = whh + (size_t)(c0 + 7 * 16 + l15) * H_ + kofs;

        float bv[8];
        if (L0) {
#pragma unroll
            for (int nt = 0; nt < 8; ++nt) bv[nt] = b0s[c0 + nt * 16 + l15];
        }

        f32x4 un[4];        // L0: loop-carried u prefetch (compiler-managed)
        uint64_t xn[8];     // L1: loop-carried xw1 prefetch (compiler-managed)
        int gateA = -1, gateB = -1, bc = -1;

        if (L0) {
            const float* up0 = u + ((size_t)(b0 + l15) * L_) * DIN + kofs;
            un[0] = *(const f32x4*)(up0);
            un[1] = *(const f32x4*)(up0 + 4);
            un[2] = *(const f32x4*)(up0 + 32);
            un[3] = *(const f32x4*)(up0 + 36);
        } else {
            if (tid < 4) {   // prologue gates: xw1 slots 0 and 1 ready
                gateA = spin_geq(FLG(16 + tid * 2 + 0), 0, gateA);
                gateB = spin_geq(FLG(16 + tid * 2 + 1), 1, gateB);
            }
            __syncthreads();
            asm volatile("" ::: "memory");
            const uint64_t* xp = (const uint64_t*)s1g + tid * 8;
#pragma unroll
            for (int i = 0; i < 8; ++i) xn[i] = AGENT_LD(xp + i);
        }

        for (int t = 0; t < L_; ++t) {
            f32x4 acc[8];
            if (L0) {
                half8 ua[2];
#pragma unroll
                for (int j = 0; j < 4; ++j) {
                    ua[0][j] = (_Float16)un[0][j]; ua[0][4 + j] = (_Float16)un[1][j];
                    ua[1][j] = (_Float16)un[2][j]; ua[1][4 + j] = (_Float16)un[3][j];
                }
                if (t + 1 < L_) {   // compiler-managed prefetch for t+1
                    const float* up = u + ((size_t)(b0 + l15) * L_ + (t + 1)) * DIN + kofs;
                    un[0] = *(const f32x4*)(up);
                    un[1] = *(const f32x4*)(up + 4);
                    un[2] = *(const f32x4*)(up + 32);
                    un[3] = *(const f32x4*)(up + 36);
                }
#pragma unroll
                for (int nt = 0; nt < 8; ++nt) {
                    acc[nt] = (f32x4){bv[nt], bv[nt], bv[nt], bv[nt]};
#pragma unroll
                    for (int kt = 0; kt < 2; ++kt) {
                        half8 wc = *(const half8*)(wcomb + (size_t)(c0 + nt * 16 + l15) * DIN + kt * 32 + kofs);
                        acc[nt] = MFMA16(ua[kt], wc, acc[nt]);
                    }
                }
            } else {
                half8 xq[4];
#pragma unroll
                for (int q = 0; q < 4; ++q) {
                    union { uint64_t qq[2]; half8 h; } uu;
                    uu.qq[0] = xn[2 * q]; uu.qq[1] = xn[2 * q + 1];
                    xq[q] = uu.h;
                }
#pragma unroll
                for (int nt = 0; nt < 8; ++nt)
#pragma unroll
                    for (int r = 0; r < 4; ++r)
                        acc[nt][r] = (float)xq[nt >> 1][(nt & 1) * 4 + r];
                if (t + 1 < L_) {   // compiler-managed prefetch for t+1 (gated last iter)
                    const uint64_t* xp = (const uint64_t*)(s1g + (size_t)((t + 1) & 7) * 8192) + tid * 8;
#pragma unroll
                    for (int i = 0; i < 8; ++i) xn[i] = AGENT_LD(xp + i);
                }
            }
            if (t > 0) {
#pragma unroll
                for (int kt = 0; kt < 16; ++kt) {
                    half8 a  = *(const half8*)&hbuf[l15][kt * 32 + kofs];
                    half8 s4 = *(const half8*)(wst4 + kt * 32);
                    half8 s5 = *(const half8*)(wst5 + kt * 32);
                    half8 s6 = *(const half8*)(wst6 + kt * 32);
                    half8 s7 = *(const half8*)(wst7 + kt * 32);
                    acc[0] = MFMA16(a, wv[0][kt], acc[0]);
                    acc[1] = MFMA16(a, wv[1][kt], acc[1]);
                    acc[2] = MFMA16(a, wv[2][kt], acc[2]);
                    acc[3] = MFMA16(a, wv[3][kt], acc[3]);
                    acc[4] = MFMA16(a, s4, acc[4]);
                    acc[5] = MFMA16(a, s5, acc[5]);
                    acc[6] = MFMA16(a, s6, acc[6]);
                    acc[7] = MFMA16(a, s7, acc[7]);
                }
            }
            _Float16 th[8][4];
#pragma unroll
            for (int nt = 0; nt < 8; ++nt)
#pragma unroll
                for (int r = 0; r < 4; ++r)
                    th[nt][r] = (_Float16)tanh_fast(acc[nt][r]);
            __syncthreads();                                   // B1: hbuf(t-1) reads done
#pragma unroll
            for (int nt = 0; nt < 8; ++nt)
#pragma unroll
                for (int r = 0; r < 4; ++r)
                    hbuf[lg * 4 + r][c0 + nt * 16 + l15] = th[nt][r];
            __syncthreads();                                   // B2: hbuf(t) complete
            {   // coalesced publish: LDS -> global ring (compiler-managed atomic stores)
                const int row = tid >> 4, cb = (tid & 15) * 32;
                const uint64_t* hsrc = (const uint64_t*)&hbuf[row][cb];
                uint64_t* hdq = (uint64_t*)(hdst + (size_t)(t & 7) * 8192 + row * H_ + cb);
#pragma unroll
                for (int i = 0; i < 8; ++i) AGENT_ST(hdq + i, hsrc[i]);
            }
            // gates for t+1 (overlap spins with the store drain below)
            if (L0) {
                if (tid >= 8 && tid < 16) bc = spin_geq(FLG(8 + (tid - 8)), t - 7, bc);
            } else {
                if (tid < 4 && t + 2 < L_) {
                    if (((t + 2) & 1) == 0) gateA = spin_geq(FLG(16 + tid * 2 + 0), t + 2, gateA);
                    else                    gateB = spin_geq(FLG(16 + tid * 2 + 1), t + 2, gateB);
                }
                if (tid >= 8 && tid < 10) bc = spin_geq(FLG(3 + (tid - 8)), t - 7, bc);
            }
            asm volatile("s_waitcnt vmcnt(0)" ::: "memory");   // h(t) stores at L3
            __syncthreads();                                   // B3: all waves drained+gated
            if (tid == 0) {
                AGENT_ST(FLG(L0 ? 0 : 2), t);                  // FH0 / FH1
                if (!L0) AGENT_ST(FLG(1), t);                  // FC1 (xw1_t consumed)
            }
        }

    } else if (role <= 3) {
        // ================= G3 (parity p) =================
        const int p = role - 2;
        const int n = w * 16 + l15;   // 256 thr, w=0..3 -> all 64 cols
        half8 wof[16];
#pragma unroll
        for (int kt = 0; kt < 16; ++kt) {
            wof[kt] = *(const half8*)(woutw + (size_t)n * H_ + kt * 32 + kofs);
            PINH8(wof[kt]);
        }
        int fh = -1;
        for (int t = p; t < L_; t += 2) {
            if (tid == 0) fh = spin_geq(FLG(2), t, fh);
            __syncthreads();
            asm volatile("" ::: "memory");
            half8 a[16];
            ld_frags16_sc(h1g + (size_t)(t & 7) * 8192 + l15 * H_ + kofs, a);
            f32x4 acc = (f32x4){0.f, 0.f, 0.f, 0.f};
#pragma unroll
            for (int kt = 0; kt < 16; ++kt) acc = MFMA16(a[kt], wof[kt], acc);
            __syncthreads();                     // all waves' h1 reads complete
            if (tid == 0) AGENT_ST(FLG(3 + p), t);
#pragma unroll
            for (int r = 0; r < 4; ++r)
                out[((size_t)(b0 + lg * 4 + r) * L_ + t) * DOUT + n] = acc[r];
        }

    } else {
        // ================= X1_{j,p} =================
        const int j = (role - 4) >> 1, p = (role - 4) & 1;
        const int c0 = j * 128 + w * 32;
        half8 wif[2][16]; float bvx[2];
#pragma unroll
        for (int nt = 0; nt < 2; ++nt) {
            const int n = c0 + nt * 16 + l15;
#pragma unroll
            for (int kt = 0; kt < 16; ++kt) {
                wif[nt][kt] = *(const half8*)(wih1w + (size_t)n * H_ + kt * 32 + kofs);
                PINH8(wif[nt][kt]);
            }
            bvx[nt] = b1s[n];
        }
        int fh = -1, fc = -1;
        for (int t = p; t < L_; t += 2) {
            if (tid == 0) {
                fh = spin_geq(FLG(0), t, fh);         // h0_t published
                fc = spin_geq(FLG(1), t - 8, fc);     // xw1 slot free
            }
            __syncthreads();
            asm volatile("" ::: "memory");
            half8 a[16];
            ld_frags16_sc(h0g + (size_t)(t & 7) * 8192 + l15 * H_ + kofs, a);
            f32x4 acc0 = (f32x4){bvx[0], bvx[0], bvx[0], bvx[0]};
            f32x4 acc1 = (f32x4){bvx[1], bvx[1], bvx[1], bvx[1]};
#pragma unroll
            for (int kt = 0; kt < 16; ++kt) {
                acc0 = MFMA16(a[kt], wif[0][kt], acc0);
                acc1 = MFMA16(a[kt], wif[1][kt], acc1);
            }
            union { half8 h; uint64_t q[2]; } uo;
#pragma unroll
            for (int r = 0; r < 4; ++r) {
                uo.h[r] = (_Float16)acc0[r];
                uo.h[4 + r] = (_Float16)acc1[r];
            }
            uint64_t* op = (uint64_t*)(s1g + (size_t)(t & 7) * 8192 + j * 2048 + l * 32 + w * 8);
            AGENT_ST(op, uo.q[0]);
            AGENT_ST(op + 1, uo.q[1]);
            asm volatile("s_waitcnt vmcnt(0)" ::: "memory");
            __syncthreads();
            if (tid == 0) {
                AGENT_ST(FLG(16 + j * 2 + p), t);   // FX1
                AGENT_ST(FLG(8 + j * 2 + p), t);    // FCH0 (h0_t consumed)
            }
        }
    }
#undef FLG
}

// ---------------- launch ----------------
extern "C" void kernel_launch(void* const* d_in, const int* in_sizes, int n_in,
                              void* d_out, int out_size, void* d_ws, size_t ws_size,
                              hipStream_t stream) {
    const float* u    = (const float*)d_in[0];
    const float* Win  = (const float*)d_in[1];
    const float* Wih0 = (const float*)d_in[2];
    const float* Whh0 = (const float*)d_in[3];
    const float* bih0 = (const float*)d_in[4];
    const float* bhh0 = (const float*)d_in[5];
    const float* Wih1 = (const float*)d_in[6];
    const float* Whh1 = (const float*)d_in[7];
    const float* bih1 = (const float*)d_in[8];
    const float* bhh1 = (const float*)d_in[9];
    const float* Wout = (const float*)d_in[10];
    (void)in_sizes; (void)n_in; (void)out_size; (void)ws_size;

    char* ws = (char*)d_ws;
    size_t off = 0;
    auto alloc = [&](size_t bytes) {
        char* p = ws + off;
        off += (bytes + 255) & ~(size_t)255;
        return p;
    };
    // total workspace ~5 MB
    _Float16* wcomb = (_Float16*)alloc((size_t)H_ * DIN * 2);
    _Float16* whh0h = (_Float16*)alloc((size_t)H_ * H_ * 2);
    _Float16* wih1h = (_Float16*)alloc((size_t)H_ * H_ * 2);
    _Float16* whh1h = (_Float16*)alloc((size_t)H_ * H_ * 2);
    _Float16* wouth = (_Float16*)alloc((size_t)DOUT * H_ * 2);
    float*    b0s   = (float*)alloc(H_ * 4);
    float*    b1s   = (float*)alloc(H_ * 4);
    _Float16* slot1 = (_Float16*)alloc((size_t)8 * 8 * 8192 * 2);
    _Float16* h0s   = (_Float16*)alloc((size_t)8 * 8 * 8192 * 2);
    _Float16* h1s   = (_Float16*)alloc((size_t)8 * 8 * 8192 * 2);
    int*      flags = (int*)alloc(256 * FSTR * 4);

    k_init_flags<<<1, 256, 0, stream>>>(flags);
    k_prep_w<<<1024, 256, 0, stream>>>(Whh0, Wih1, Whh1, Wout, bih0, bhh0, bih1, bhh1,
                                       whh0h, wih1h, whh1h, wouth, b0s, b1s);
    k_wcomb<<<512, 64, 0, stream>>>(Wih0, Win, wcomb);

    k_pipe3<<<96, 256, 0, stream>>>(u, wcomb, whh0h, wih1h, whh1h, wouth, b0s, b1s,
                                    (float*)d_out, slot1, h0s, h1s, flags);
}

// Round 9
// 5154.431 us; speedup vs baseline: 2.6783x; 2.6783x over previous
//
#include <hip/hip_runtime.h>
#include <hip/hip_fp16.h>

#define B_   128
#define L_   1024
#define DIN  64
#define H_   512
#define DOUT 64

typedef _Float16 half8 __attribute__((ext_vector_type(8)));
typedef float    f32x4 __attribute__((ext_vector_type(4)));

#define FSTR 16            // flag stride in ints (64B)
#define SPIN_CAP (1<<16)   // ctr-gate cap  (~13ms worst: loud failure, no hang)
#define POLL_CAP (1<<14)   // value-poll cap (~15ms worst)
#define POISON   0x7C00u   // f16 +inf — tanh outputs in [-1,1] can never equal it

#define MFMA16(a,b,c) __builtin_amdgcn_mfma_f32_16x16x32_f16((a),(b),(c),0,0,0)
#define PINH8(x) asm volatile("" : "+v"(x))
#define AGENT_ST(p, v) __hip_atomic_store((p), (v), __ATOMIC_RELAXED, __HIP_MEMORY_SCOPE_AGENT)
#define AGENT_LD(p)    __hip_atomic_load((p), __ATOMIC_RELAXED, __HIP_MEMORY_SCOPE_AGENT)

// ---------------- init: poison h rings + reset ctrs (re-run every launch -> replay safe) ----
__global__ void k_init(int* flags, unsigned int* hx0u, unsigned int* hx1u) {
    int i = blockIdx.x * blockDim.x + threadIdx.x;
    const int NRING = 8 * 4 * 16 * H_ / 2;   // uint32 count per ring = 131072
    if (i < NRING) { hx0u[i] = 0x7C007C00u; hx1u[i] = 0x7C007C00u; }
    if (i < 128) flags[i * FSTR] = -1;
}

// ---------------- cast weights to f16 + bias sums ----------------
__global__ void k_prep_w(const float* __restrict__ whh0, const float* __restrict__ wih1,
                         const float* __restrict__ whh1, const float* __restrict__ wout,
                         const float* __restrict__ bih0, const float* __restrict__ bhh0,
                         const float* __restrict__ bih1, const float* __restrict__ bhh1,
                         _Float16* __restrict__ o0, _Float16* __restrict__ o1,
                         _Float16* __restrict__ o2, _Float16* __restrict__ o3,
                         float* __restrict__ b0s, float* __restrict__ b1s) {
    const int NW = H_ * H_;
    const int total = 3 * NW + DOUT * H_ + 2 * H_;
    int i  = blockIdx.x * blockDim.x + threadIdx.x;
    int st = gridDim.x * blockDim.x;
    for (; i < total; i += st) {
        if      (i < NW)            o0[i]          = (_Float16)whh0[i];
        else if (i < 2 * NW)        o1[i - NW]     = (_Float16)wih1[i - NW];
        else if (i < 3 * NW)        o2[i - 2 * NW] = (_Float16)whh1[i - 2 * NW];
        else if (i < 3 * NW + DOUT * H_) o3[i - 3 * NW] = (_Float16)wout[i - 3 * NW];
        else if (i < 3 * NW + DOUT * H_ + H_) {
            int j = i - (3 * NW + DOUT * H_);
            b0s[j] = bih0[j] + bhh0[j];
        } else {
            int j = i - (3 * NW + DOUT * H_ + H_);
            b1s[j] = bih1[j] + bhh1[j];
        }
    }
}

// ---------------- wcomb[g][d] = sum_h W_ih0[g][h] * W_in[h][d] ----------------
__global__ void k_wcomb(const float* __restrict__ wih0, const float* __restrict__ win,
                        _Float16* __restrict__ o) {
    int g = blockIdx.x;    // 512
    int d = threadIdx.x;   // 64
    float acc = 0.f;
    for (int h = 0; h < H_; ++h)
        acc += wih0[g * H_ + h] * win[h * DIN + d];
    o[g * DIN + d] = (_Float16)acc;
}

// ---------------- helpers ----------------
__device__ __forceinline__ int spin_geq(const int* fp, int tgt, int cached) {
    if (cached >= tgt) return cached;      // cached-monotone: free once satisfied
    int v = AGENT_LD(fp);
    int it = 0;
    while (v < tgt && ++it < SPIN_CAP) v = AGENT_LD(fp);
    return v;
}

__device__ __forceinline__ float tanh_fast(float v) {
    float e = __expf(2.f * v);
    return 1.f - 2.f / (e + 1.f);
}

// single 16B device-coherent store (atomic at L3 granularity)
__device__ __forceinline__ void st16_sc(void* p, half8 v) {
    asm volatile("global_store_dwordx4 %0, %1, off sc0 sc1" :: "v"(p), "v"(v) : "memory");
}

// 16 x 16B sc loads from base + i*64B, internal vmcnt(0): outputs valid at asm end
__device__ __forceinline__ void ld16_w(const _Float16* base, half8 f[16]) {
    asm volatile(
        "global_load_dwordx4 %0, %16, off sc0 sc1\n\t"
        "global_load_dwordx4 %1, %16, off offset:64 sc0 sc1\n\t"
        "global_load_dwordx4 %2, %16, off offset:128 sc0 sc1\n\t"
        "global_load_dwordx4 %3, %16, off offset:192 sc0 sc1\n\t"
        "global_load_dwordx4 %4, %16, off offset:256 sc0 sc1\n\t"
        "global_load_dwordx4 %5, %16, off offset:320 sc0 sc1\n\t"
        "global_load_dwordx4 %6, %16, off offset:384 sc0 sc1\n\t"
        "global_load_dwordx4 %7, %16, off offset:448 sc0 sc1\n\t"
        "global_load_dwordx4 %8, %16, off offset:512 sc0 sc1\n\t"
        "global_load_dwordx4 %9, %16, off offset:576 sc0 sc1\n\t"
        "global_load_dwordx4 %10, %16, off offset:640 sc0 sc1\n\t"
        "global_load_dwordx4 %11, %16, off offset:704 sc0 sc1\n\t"
        "global_load_dwordx4 %12, %16, off offset:768 sc0 sc1\n\t"
        "global_load_dwordx4 %13, %16, off offset:832 sc0 sc1\n\t"
        "global_load_dwordx4 %14, %16, off offset:896 sc0 sc1\n\t"
        "global_load_dwordx4 %15, %16, off offset:960 sc0 sc1\n\t"
        "s_waitcnt vmcnt(0)"
        : "=&v"(f[0]), "=&v"(f[1]), "=&v"(f[2]), "=&v"(f[3]),
          "=&v"(f[4]), "=&v"(f[5]), "=&v"(f[6]), "=&v"(f[7]),
          "=&v"(f[8]), "=&v"(f[9]), "=&v"(f[10]), "=&v"(f[11]),
          "=&v"(f[12]), "=&v"(f[13]), "=&v"(f[14]), "=&v"(f[15])
        : "v"(base)
        : "memory");
}

// value-poll: reload 16 chunks until no chunk's first f16 is POISON.
// Each 16B chunk was written by ONE 16B store -> first-f16 valid implies chunk valid.
__device__ __forceinline__ void poll16(const _Float16* base, half8 f[16]) {
    int it = 0;
    for (;;) {
        ld16_w(base, f);
        int ok = 1;
#pragma unroll
        for (int i = 0; i < 16; ++i) {
            union { half8 h; unsigned short s[8]; } u; u.h = f[i];
            ok &= (u.s[0] != POISON);
        }
        if (__all(ok) || ++it > POLL_CAP) break;
    }
}

// ---------------- fused persistent pipeline: poisoned-slot value sync ----------------
// grid = 104 blocks x 256 thr: g = bid&7, role = bid>>3.
//   role 0..3  : L0, col slice 128*role
//   role 4..11 : L1 (xw1 inline), col slice 64*(role-4)
//   role 12    : G3 output projection
// h rings hx0/hx1 [8][4][16][512] f16, depth-4 slots, written as 16B chunks.
// Sync: consumers poll data for non-POISON. Producers poison slot (t+1)&3 EARLY in
// step t and drain (vmcnt0) BEFORE step-t data stores => "saw t-data => poison landed".
// Anti-overwrite: progress ctr per block; producers gate poison on consumers' ctr >= t-2.
__global__ __launch_bounds__(256, 1)
void k_pipeline(const float* __restrict__ u,
                const _Float16* __restrict__ wcomb,   // [512][64]
                const _Float16* __restrict__ whh0w,   // [512][512]
                const float* __restrict__ b0s,
                const _Float16* __restrict__ wih1w,   // [512][512]
                const _Float16* __restrict__ whh1w,   // [512][512]
                const float* __restrict__ b1s,
                const _Float16* __restrict__ woutw,   // [64][512]
                float* __restrict__ out,              // [B_*L_][64] fp32
                _Float16* __restrict__ hx0,
                _Float16* __restrict__ hx1,
                int* __restrict__ flags) {            // ctr[bid] at flags[bid*FSTR]
    const int bid = blockIdx.x;
    const int g = bid & 7, role = bid >> 3;
    const int tid = threadIdx.x;
    const int l = tid & 63, w = tid >> 6;
    const int l15 = l & 15, lg = l >> 4, kofs = lg * 8;
    const int b0 = g * 16;
    _Float16* hx0g = hx0 + (size_t)g * (4 * 16 * H_);
    _Float16* hx1g = hx1 + (size_t)g * (4 * 16 * H_);
    int* myctr = flags + bid * FSTR;

    __shared__ _Float16 hlt[16][136];   // LDS transpose staging (L0:128 cols, L1:64)

    union { unsigned short s[8]; half8 h; } pv;
#pragma unroll
    for (int i = 0; i < 8; ++i) pv.s[i] = POISON;
    const half8 poisonv = pv.h;

    if (role < 4) {
        // ================= L0 =================
        const int s = role;
        const int col0 = s * 128 + w * 32;
        half8 whf[2][16], wcf[2][2];
#pragma unroll
        for (int nt = 0; nt < 2; ++nt) {
            const int n = col0 + nt * 16 + l15;
#pragma unroll
            for (int kt = 0; kt < 16; ++kt) {
                whf[nt][kt] = *(const half8*)(whh0w + (size_t)n * H_ + kt * 32 + kofs);
                PINH8(whf[nt][kt]);
            }
#pragma unroll
            for (int kt = 0; kt < 2; ++kt) {
                wcf[nt][kt] = *(const half8*)(wcomb + (size_t)n * DIN + kt * 32 + kofs);
                PINH8(wcf[nt][kt]);
            }
        }
        const float bv0 = b0s[col0 + l15], bv1 = b0s[col0 + 16 + l15];
        // consumers of h0: all L0 (roles 0-3) + all L1 (roles 4-11) = 12 blocks
        const int* gatep = (tid < 12) ? flags + (g + 8 * tid) * FSTR : nullptr;
        int gc = -1;
        const int prow = tid >> 4, pc8 = tid & 15;    // this thread's 16B chunk coords

        for (int t = 0; t < L_; ++t) {
            if (t >= 3 && gatep) gc = spin_geq(gatep, t - 2, gc);
            __syncthreads();                                    // B0: gate passed
            if (t + 1 < L_)                                     // poison slot t+1 (own chunks)
                st16_sc(hx0g + (size_t)(((t + 1) & 3)) * (16 * H_)
                        + (size_t)prow * H_ + s * 128 + pc8 * 8, poisonv);
            // u part (plain cached loads; independent)
            const float* up = u + ((size_t)(b0 + l15) * L_ + t) * DIN + kofs;
            f32x4 u0a = *(const f32x4*)(up);
            f32x4 u0b = *(const f32x4*)(up + 4);
            f32x4 u1a = *(const f32x4*)(up + 32);
            f32x4 u1b = *(const f32x4*)(up + 36);
            half8 ua[2];
#pragma unroll
            for (int j = 0; j < 4; ++j) {
                ua[0][j] = (_Float16)u0a[j]; ua[0][4 + j] = (_Float16)u0b[j];
                ua[1][j] = (_Float16)u1a[j]; ua[1][4 + j] = (_Float16)u1b[j];
            }
            f32x4 acc0 = (f32x4){bv0, bv0, bv0, bv0};
            f32x4 acc1 = (f32x4){bv1, bv1, bv1, bv1};
#pragma unroll
            for (int kt = 0; kt < 2; ++kt) {
                acc0 = MFMA16(ua[kt], wcf[0][kt], acc0);
                acc1 = MFMA16(ua[kt], wcf[1][kt], acc1);
            }
            if (t > 0) {
                half8 a[16];
                poll16(hx0g + (size_t)((t - 1) & 3) * (16 * H_) + (size_t)l15 * H_ + kofs, a);
#pragma unroll
                for (int kt = 0; kt < 16; ++kt) {
                    acc0 = MFMA16(a[kt], whf[0][kt], acc0);
                    acc1 = MFMA16(a[kt], whf[1][kt], acc1);
                }
            }
            _Float16 th0[4], th1[4];
#pragma unroll
            for (int r = 0; r < 4; ++r) {
                th0[r] = (_Float16)tanh_fast(acc0[r]);
                th1[r] = (_Float16)tanh_fast(acc1[r]);
            }
            __syncthreads();                                    // B1: prior LDS reads done
#pragma unroll
            for (int r = 0; r < 4; ++r) {
                hlt[lg * 4 + r][w * 32 + l15]      = th0[r];
                hlt[lg * 4 + r][w * 32 + 16 + l15] = th1[r];
            }
            __syncthreads();                                    // B2: hlt(t) complete
            {   // 16B-chunk publish (no drain after: flight overlaps next step)
                half8 ch = *(const half8*)&hlt[prow][pc8 * 8];
                asm volatile("s_waitcnt vmcnt(0)" ::: "memory");  // poisons (issued ~step ago + this step early) landed
                st16_sc(hx0g + (size_t)(t & 3) * (16 * H_)
                        + (size_t)prow * H_ + s * 128 + pc8 * 8, ch);
            }
            if (tid == 0) AGENT_ST(myctr, t);
        }
    } else if (role < 12) {
        // ================= L1 (xw1 inline) =================
        const int s = role - 4;
        const int n = s * 64 + w * 16 + l15;
        half8 wif[16], whf[16];
#pragma unroll
        for (int kt = 0; kt < 16; ++kt) {
            wif[kt] = *(const half8*)(wih1w + (size_t)n * H_ + kt * 32 + kofs);
            PINH8(wif[kt]);
            whf[kt] = *(const half8*)(whh1w + (size_t)n * H_ + kt * 32 + kofs);
            PINH8(whf[kt]);
        }
        const float bv = b1s[n];
        // consumers of h1: all L1 (roles 4-11) + G3 (role 12) = 9 blocks
        const int* gatep = (tid < 9) ? flags + (g + 8 * (4 + tid)) * FSTR : nullptr;
        int gc = -1;
        const int prow = tid >> 3, pc8 = tid & 7;   // chunk coords (threads 0..127)

        for (int t = 0; t < L_; ++t) {
            if (t >= 3 && gatep) gc = spin_geq(gatep, t - 2, gc);
            __syncthreads();                                    // B0
            if (t + 1 < L_ && tid < 128)
                st16_sc(hx1g + (size_t)((t + 1) & 3) * (16 * H_)
                        + (size_t)prow * H_ + s * 64 + pc8 * 8, poisonv);
            f32x4 acch = (f32x4){0.f, 0.f, 0.f, 0.f};
            if (t > 0) {   // h1_{t-1}: old data, likely first-poll hit
                half8 a1[16];
                poll16(hx1g + (size_t)((t - 1) & 3) * (16 * H_) + (size_t)l15 * H_ + kofs, a1);
#pragma unroll
                for (int kt = 0; kt < 16; ++kt)
                    acch = MFMA16(a1[kt], whf[kt], acch);
            }
            f32x4 accx = (f32x4){bv, bv, bv, bv};
            {   // h0_t: fresh; poll after the whf chain gave it flight time
                half8 a0[16];
                poll16(hx0g + (size_t)(t & 3) * (16 * H_) + (size_t)l15 * H_ + kofs, a0);
#pragma unroll
                for (int kt = 0; kt < 16; ++kt)
                    accx = MFMA16(a0[kt], wif[kt], accx);
            }
            _Float16 th[4];
#pragma unroll
            for (int r = 0; r < 4; ++r) th[r] = (_Float16)tanh_fast(accx[r] + acch[r]);
            __syncthreads();                                    // B1
#pragma unroll
            for (int r = 0; r < 4; ++r)
                hlt[lg * 4 + r][w * 16 + l15] = th[r];
            __syncthreads();                                    // B2
            if (tid < 128) {
                half8 ch = *(const half8*)&hlt[prow][pc8 * 8];
                asm volatile("s_waitcnt vmcnt(0)" ::: "memory");
                st16_sc(hx1g + (size_t)(t & 3) * (16 * H_)
                        + (size_t)prow * H_ + s * 64 + pc8 * 8, ch);
            }
            if (tid == 0) AGENT_ST(myctr, t);
        }
    } else {
        // ================= G3 (output projection) =================
        const int n = w * 16 + l15;
        half8 wof[16];
#pragma unroll
        for (int kt = 0; kt < 16; ++kt) {
            wof[kt] = *(const half8*)(woutw + (size_t)n * H_ + kt * 32 + kofs);
            PINH8(wof[kt]);
        }
        for (int t = 0; t < L_; ++t) {
            half8 a[16];
            poll16(hx1g + (size_t)(t & 3) * (16 * H_) + (size_t)l15 * H_ + kofs, a);
            f32x4 acc = (f32x4){0.f, 0.f, 0.f, 0.f};
#pragma unroll
            for (int kt = 0; kt < 16; ++kt)
                acc = MFMA16(a[kt], wof[kt], acc);
            __syncthreads();                 // all waves consumed h1_t
            if (tid == 0) AGENT_ST(myctr, t);
#pragma unroll
            for (int r = 0; r < 4; ++r)
                out[((size_t)(b0 + lg * 4 + r) * L_ + t) * DOUT + n] = acc[r];
        }
    }
}

// ---------------- launch ----------------
extern "C" void kernel_launch(void* const* d_in, const int* in_sizes, int n_in,
                              void* d_out, int out_size, void* d_ws, size_t ws_size,
                              hipStream_t stream) {
    const float* u    = (const float*)d_in[0];
    const float* Win  = (const float*)d_in[1];
    const float* Wih0 = (const float*)d_in[2];
    const float* Whh0 = (const float*)d_in[3];
    const float* bih0 = (const float*)d_in[4];
    const float* bhh0 = (const float*)d_in[5];
    const float* Wih1 = (const float*)d_in[6];
    const float* Whh1 = (const float*)d_in[7];
    const float* bih1 = (const float*)d_in[8];
    const float* bhh1 = (const float*)d_in[9];
    const float* Wout = (const float*)d_in[10];
    (void)in_sizes; (void)n_in; (void)out_size; (void)ws_size;

    char* ws = (char*)d_ws;
    size_t off = 0;
    auto alloc = [&](size_t bytes) {
        char* p = ws + off;
        off += (bytes + 255) & ~(size_t)255;
        return p;
    };
    // total workspace ~3.3 MB
    _Float16* wcomb = (_Float16*)alloc((size_t)H_ * DIN * 2);
    _Float16* whh0h = (_Float16*)alloc((size_t)H_ * H_ * 2);
    _Float16* wih1h = (_Float16*)alloc((size_t)H_ * H_ * 2);
    _Float16* whh1h = (_Float16*)alloc((size_t)H_ * H_ * 2);
    _Float16* wouth = (_Float16*)alloc((size_t)DOUT * H_ * 2);
    float*    b0s   = (float*)alloc(H_ * 4);
    float*    b1s   = (float*)alloc(H_ * 4);
    _Float16* hx0   = (_Float16*)alloc((size_t)8 * 4 * 16 * H_ * 2);
    _Float16* hx1   = (_Float16*)alloc((size_t)8 * 4 * 16 * H_ * 2);
    int*      flags = (int*)alloc(128 * FSTR * 4);

    k_init<<<512, 256, 0, stream>>>(flags, (unsigned int*)hx0, (unsigned int*)hx1);
    k_prep_w<<<1024, 256, 0, stream>>>(Whh0, Wih1, Whh1, Wout, bih0, bhh0, bih1, bhh1,
                                       whh0h, wih1h, whh1h, wouth, b0s, b1s);
    k_wcomb<<<512, 64, 0, stream>>>(Wih0, Win, wcomb);

    k_pipeline<<<104, 256, 0, stream>>>(u, wcomb, whh0h, b0s, wih1h, whh1h, b1s, wouth,
                                        (float*)d_out, hx0, hx1, flags);
}